// Round 10
// baseline (2188.122 us; speedup 1.0000x reference)
//
#include <hip/hip_runtime.h>
#include <cstddef>

#define DIN 128
#define DD 64

typedef unsigned short bfu;   // raw bf16 bits
typedef __attribute__((ext_vector_type(8))) short bf16x8;
typedef __attribute__((ext_vector_type(4))) float f32x4;

static __device__ __forceinline__ float bf2f(bfu u) {
    union { unsigned int i; float f; } v; v.i = ((unsigned int)u) << 16; return v.f;
}
static __device__ __forceinline__ bfu f2bf(float f) {
    union { float f; unsigned int i; } v; v.f = f;
    unsigned int r = v.i + 0x7FFFu + ((v.i >> 16) & 1u);   // round-nearest-even
    return (bfu)(r >> 16);
}
static __device__ __forceinline__ float4 bf4_to_f4(ushort4 u) {
    return make_float4(bf2f(u.x), bf2f(u.y), bf2f(u.z), bf2f(u.w));
}
static __device__ __forceinline__ ushort4 f4_to_bf4(float4 f) {
    ushort4 u; u.x = f2bf(f.x); u.y = f2bf(f.y); u.z = f2bf(f.z); u.w = f2bf(f.w); return u;
}
static __device__ __forceinline__ float sigmoidf_(float x) {
    return 1.0f / (1.0f + __expf(-x));
}

// ---------------------------------------------------------------------------
// h0 = nodes_feat @ W_h + b_h   [N,128]@[128,64] -> f32
// ---------------------------------------------------------------------------
__global__ __launch_bounds__(256) void embed_h_v10(
    const float* __restrict__ x, const float* __restrict__ Wh,
    const float* __restrict__ bh, float* __restrict__ h, int N)
{
    __shared__ float w[DIN][DD];    // 32 KB
    __shared__ float xs[32][DIN];   // 16 KB
    for (int i = threadIdx.x; i < DIN * DD / 4; i += 256)
        ((float4*)w)[i] = ((const float4*)Wh)[i];
    int row0 = blockIdx.x * 32;
    for (int i = threadIdx.x; i < 32 * DIN / 4; i += 256) {
        int r = i >> 5, k = (i & 31) * 4;
        int row = row0 + r;
        float4 v = make_float4(0.f, 0.f, 0.f, 0.f);
        if (row < N) v = *(const float4*)(x + (size_t)row * DIN + k);
        *(float4*)(&xs[r][k]) = v;
    }
    __syncthreads();
    int rl = threadIdx.x >> 6;
    int c  = threadIdx.x & 63;
    float b = bh[c];
    for (int rr = 0; rr < 8; ++rr) {
        int r = rl * 8 + rr;
        int row = row0 + r;
        if (row >= N) break;
        float acc = b;
        #pragma unroll
        for (int k = 0; k < DIN; k += 4) {
            float4 xv = *(const float4*)(&xs[r][k]);
            acc += xv.x * w[k][c] + xv.y * w[k+1][c] + xv.z * w[k+2][c] + xv.w * w[k+3][c];
        }
        h[(size_t)row * DD + c] = acc;
    }
}

// ---------------------------------------------------------------------------
// CSR build (by dst): histogram -> 3-phase exclusive scan -> scatter
// ---------------------------------------------------------------------------
__global__ void csr_hist_v10(const int* __restrict__ dst, int* __restrict__ counts, int E)
{
    for (int i = blockIdx.x * blockDim.x + threadIdx.x; i < E; i += gridDim.x * blockDim.x)
        atomicAdd(&counts[dst[i]], 1);
}

__global__ void csr_scan_a_v10(const int* __restrict__ counts, int* __restrict__ part,
                               int M, int CH)
{
    __shared__ int sd[256];
    int b = blockIdx.x, t = threadIdx.x;
    int idx = b * CH + t;
    int v = (t < CH && idx < M) ? counts[idx] : 0;
    sd[t] = v; __syncthreads();
    for (int off = 128; off > 0; off >>= 1) {
        if (t < off) sd[t] += sd[t + off];
        __syncthreads();
    }
    if (t == 0) part[b] = sd[0];
}

__global__ void csr_scan_b_v10(int* __restrict__ part)
{
    __shared__ int sd[256];
    int t = threadIdx.x;
    int v = part[t];
    sd[t] = v; __syncthreads();
    for (int off = 1; off < 256; off <<= 1) {
        int u = (t >= off) ? sd[t - off] : 0;
        __syncthreads();
        sd[t] += u;
        __syncthreads();
    }
    part[t] = sd[t] - v;   // exclusive
}

__global__ void csr_scan_c_v10(const int* __restrict__ counts, const int* __restrict__ part,
                               int* __restrict__ offsets, int* __restrict__ cursor,
                               int M, int CH)
{
    __shared__ int sd[256];
    int b = blockIdx.x, t = threadIdx.x;
    int idx = b * CH + t;
    int v = (t < CH && idx < M) ? counts[idx] : 0;
    sd[t] = v; __syncthreads();
    for (int off = 1; off < 256; off <<= 1) {
        int u = (t >= off) ? sd[t - off] : 0;
        __syncthreads();
        sd[t] += u;
        __syncthreads();
    }
    int excl = sd[t] - v + part[b];
    if (t < CH && idx < M) { offsets[idx] = excl; cursor[idx] = excl; }
}

__global__ void csr_scatter_v10(const int* __restrict__ dst, int* __restrict__ cursor,
                                int* __restrict__ csr_eid, int E)
{
    for (int i = blockIdx.x * blockDim.x + threadIdx.x; i < E; i += gridDim.x * blockDim.x) {
        int p = atomicAdd(&cursor[dst[i]], 1);
        csr_eid[p] = i;
    }
}

__global__ void perm_build_v10(const int* __restrict__ csr_eid, const int* __restrict__ esrc,
                               const float* __restrict__ enorm,
                               unsigned short* __restrict__ src_p,
                               float* __restrict__ enorm_p, int E)
{
    for (int i = blockIdx.x * blockDim.x + threadIdx.x; i < E; i += gridDim.x * blockDim.x) {
        int eid = csr_eid[i];
        src_p[i] = (unsigned short)esrc[eid];
        enorm_p[i] = enorm[eid];
    }
}

__global__ __launch_bounds__(256) void embed_e_perm_v10(
    const float* __restrict__ ef, const float* __restrict__ We,
    const float* __restrict__ be, const int* __restrict__ csr_eid,
    bfu* __restrict__ e, int E)
{
    int c = (threadIdx.x & 15) * 4;
    float4 w = *(const float4*)(We + c);
    float4 b = *(const float4*)(be + c);
    int total = E * 16;
    int stride = gridDim.x * blockDim.x;
    for (int u = blockIdx.x * blockDim.x + threadIdx.x; u < total; u += stride) {
        int j = u >> 4;
        float f = ef[csr_eid[j]];
        float4 o;
        o.x = f * w.x + b.x; o.y = f * w.y + b.y;
        o.z = f * w.z + b.z; o.w = f * w.w + b.w;
        *(ushort4*)(e + (size_t)j * DD + c) = f4_to_bf4(o);
    }
}

// ---------------------------------------------------------------------------
// node_mm4 v10: [optional fused h-apply of PREVIOUS layer: h = h +
// relu(A_h*x + B_h), written back] then 4 waves, one matrix each:
// wave0: Ah -> hrawA (f32); wave1: Bh -> DBh[2c+1]; wave2: Dh -> DBh[2c];
// wave3: Eh -> Eh (bf16)
// ---------------------------------------------------------------------------
__global__ __launch_bounds__(256) void node_mm4_v10(
    float* __restrict__ h, const float* __restrict__ hrawX,
    const float* __restrict__ bnAB, int apply,
    const float* __restrict__ Wa, const float* __restrict__ ba,
    const float* __restrict__ Wb, const float* __restrict__ bbv,
    const float* __restrict__ Wd, const float* __restrict__ bd,
    const float* __restrict__ We, const float* __restrict__ be,
    float* __restrict__ hrawA, bfu* __restrict__ DBh, bfu* __restrict__ Eh, int N)
{
    __shared__ float hs[64][DD];   // 16 KB
    int row0 = blockIdx.x * 64;
    {
        int cc4 = (threadIdx.x & 15) * 4;
        float4 A = make_float4(0,0,0,0), B = A;
        if (apply) {
            A = *(const float4*)(bnAB + 2 * DD + cc4);
            B = *(const float4*)(bnAB + 3 * DD + cc4);
        }
        for (int i = threadIdx.x; i < 64 * 16; i += 256) {
            int r = i >> 4;
            int row = row0 + r;
            float4 v = make_float4(0.f, 0.f, 0.f, 0.f);
            if (row < N) {
                size_t off = (size_t)row * DD + cc4;
                v = *(const float4*)(h + off);
                if (apply) {
                    float4 x = *(const float4*)(hrawX + off);
                    v.x += fmaxf(A.x * x.x + B.x, 0.f);
                    v.y += fmaxf(A.y * x.y + B.y, 0.f);
                    v.z += fmaxf(A.z * x.z + B.z, 0.f);
                    v.w += fmaxf(A.w * x.w + B.w, 0.f);
                    *(float4*)(h + off) = v;
                }
            }
            *(float4*)(&hs[r][cc4]) = v;
        }
    }
    __syncthreads();
    int m = threadIdx.x >> 6;
    int c = threadIdx.x & 63;
    const float* W    = (m == 0) ? Wa : (m == 1) ? Wb : (m == 2) ? Wd : We;
    const float* bias = (m == 0) ? ba : (m == 1) ? bbv : (m == 2) ? bd : be;
    float wcol[DD];
    #pragma unroll
    for (int k = 0; k < DD; ++k) wcol[k] = W[k * DD + c];
    float b = bias[c];
    int rmax = (N - row0 < 64) ? (N - row0) : 64;
    for (int r = 0; r < rmax; ++r) {
        float acc = b;
        #pragma unroll
        for (int k = 0; k < DD; k += 4) {
            float4 hv = *(const float4*)(&hs[r][k]);
            acc += hv.x * wcol[k] + hv.y * wcol[k+1] + hv.z * wcol[k+2] + hv.w * wcol[k+3];
        }
        size_t row = (size_t)(row0 + r);
        if (m == 0)      hrawA[row * DD + c] = acc;                // Ah (f32)
        else if (m == 1) DBh[row * 128 + 2 * c + 1] = f2bf(acc);   // B
        else if (m == 2) DBh[row * 128 + 2 * c] = f2bf(acc);       // D
        else             Eh[row * DD + c] = f2bf(acc);             // E
    }
}

// ---------------------------------------------------------------------------
// edge_fused v10: one WAVE per dst node; edges [j0,j1) in 16-row MFMA blocks.
//   A-frag: lane l loads e row (jb + l&15), k-cols 8*(l>>4)..+7 (16B) — with
//   fused prev-layer BN-apply of es: e_new = e + relu(A_e*es + B_e), stored
//   for rows < j1 (blocks are padded but never cross node boundaries).
//   eC = MFMA(e_new, Wc); er = eC + bc + Dh[src] + Eh[n]; sigmoid; num/den
//   reduced across lane-groups (shfl_xor 16/32); es = er*enorm stored.
//   x = (Ah + num/den')*nnorm -> hrawA (ld==0 lanes).  Stats accumulated.
// ---------------------------------------------------------------------------
__global__ __launch_bounds__(256) void edge_fused_v10(
    bfu* __restrict__ e, bfu* __restrict__ es,
    const float* __restrict__ Wc, const float* __restrict__ bc,
    const float* __restrict__ bnAB,
    float* __restrict__ hrawA,
    const bfu* __restrict__ DBh, const bfu* __restrict__ Eh,
    const int* __restrict__ coffs, const unsigned short* __restrict__ src_p,
    const float* __restrict__ enorm_p, const float* __restrict__ nnorm,
    float* __restrict__ stats, int N, int E, int apply, int store)
{
    __shared__ float red[4][4][DD];
    int l  = threadIdx.x & 63;
    int wid = threadIdx.x >> 6;
    int lr = l & 15;
    int ld = l >> 4;

    bf16x8 bfrag[4][2];
    #pragma unroll
    for (int ct = 0; ct < 4; ++ct)
        #pragma unroll
        for (int kh = 0; kh < 2; ++kh)
            #pragma unroll
            for (int j = 0; j < 8; ++j)
                bfrag[ct][kh][j] = (short)f2bf(Wc[(kh * 32 + 8 * ld + j) * DD + ct * 16 + lr]);

    float bcl[4];
    #pragma unroll
    for (int ct = 0; ct < 4; ++ct) bcl[ct] = bc[ct * 16 + lr];

    float A0[8], B0[8], A1[8], B1[8];
    if (apply) {
        #pragma unroll
        for (int j = 0; j < 8; ++j) {
            A0[j] = bnAB[8 * ld + j];
            B0[j] = bnAB[DD + 8 * ld + j];
            A1[j] = bnAB[32 + 8 * ld + j];
            B1[j] = bnAB[DD + 32 + 8 * ld + j];
        }
    } else {
        #pragma unroll
        for (int j = 0; j < 8; ++j) { A0[j]=B0[j]=A1[j]=B1[j]=0.f; }
    }

    float se[4]  = {0.f,0.f,0.f,0.f}, se2[4] = {0.f,0.f,0.f,0.f};
    float sh[4]  = {0.f,0.f,0.f,0.f}, sh2[4] = {0.f,0.f,0.f,0.f};

    int gw = blockIdx.x * 4 + wid;
    int gstride = gridDim.x * 4;
    for (int n = gw; n < N; n += gstride) {
        int j0 = coffs[n], j1 = coffs[n + 1];
        float num[4] = {0.f,0.f,0.f,0.f}, den[4] = {0.f,0.f,0.f,0.f};
        float ehv[4];
        #pragma unroll
        for (int ct = 0; ct < 4; ++ct) ehv[ct] = bf2f(Eh[(size_t)n * DD + ct * 16 + lr]);

        for (int jb = j0; jb < j1; jb += 16) {
            int nvalid = j1 - jb;                 // rows [0,nvalid) valid
            int arow = jb + lr;
            int lrow = (arow < E) ? arow : (E - 1);
            size_t aoff = (size_t)lrow * DD + 8 * ld;
            bf16x8 a0, a1;
            {
                bf16x8 r0 = *(const bf16x8*)(e + aoff);
                bf16x8 r1 = *(const bf16x8*)(e + aoff + 32);
                if (apply) {
                    bf16x8 s0 = *(const bf16x8*)(es + aoff);
                    bf16x8 s1 = *(const bf16x8*)(es + aoff + 32);
                    #pragma unroll
                    for (int j = 0; j < 8; ++j) {
                        float v0 = bf2f((bfu)r0[j]) + fmaxf(A0[j] * bf2f((bfu)s0[j]) + B0[j], 0.f);
                        float v1 = bf2f((bfu)r1[j]) + fmaxf(A1[j] * bf2f((bfu)s1[j]) + B1[j], 0.f);
                        a0[j] = (short)f2bf(v0);
                        a1[j] = (short)f2bf(v1);
                    }
                    if (store && lr < nvalid) {
                        *(bf16x8*)(e + aoff) = a0;
                        *(bf16x8*)(e + aoff + 32) = a1;
                    }
                } else {
                    a0 = r0; a1 = r1;
                }
            }
            // per-lane edge metadata for rows 4*ld+j
            float enr[4]; int sr[4]; bool vm[4];
            #pragma unroll
            for (int j = 0; j < 4; ++j) {
                int rj = 4 * ld + j;
                vm[j] = rj < nvalid;
                int row = jb + (vm[j] ? rj : 0);
                enr[j] = enorm_p[row];
                sr[j]  = src_p[row];
            }
            #pragma unroll
            for (int ct = 0; ct < 4; ++ct) {
                f32x4 acc = {0.f, 0.f, 0.f, 0.f};
                acc = __builtin_amdgcn_mfma_f32_16x16x32_bf16(a0, bfrag[ct][0], acc, 0, 0, 0);
                acc = __builtin_amdgcn_mfma_f32_16x16x32_bf16(a1, bfrag[ct][1], acc, 0, 0, 0);
                #pragma unroll
                for (int j = 0; j < 4; ++j) {
                    ushort2 db = *(const ushort2*)(DBh + (size_t)sr[j] * 128 + 2 * (ct * 16 + lr));
                    float er = acc[j] + bcl[ct] + bf2f(db.x) + ehv[ct];
                    float sg = sigmoidf_(er);
                    float esv = er * enr[j];
                    if (vm[j]) {
                        num[ct] += sg * bf2f(db.y);
                        den[ct] += sg;
                        se[ct]  += esv;
                        se2[ct] += esv * esv;
                        if (store)
                            es[(size_t)(jb + 4 * ld + j) * DD + ct * 16 + lr] = f2bf(esv);
                    }
                }
            }
        }
        // reduce num/den across the 4 lane-groups holding the same channels
        #pragma unroll
        for (int ct = 0; ct < 4; ++ct) {
            num[ct] += __shfl_xor(num[ct], 16); num[ct] += __shfl_xor(num[ct], 32);
            den[ct] += __shfl_xor(den[ct], 16); den[ct] += __shfl_xor(den[ct], 32);
        }
        if (ld == 0) {
            float nn = nnorm[n];
            #pragma unroll
            for (int ct = 0; ct < 4; ++ct) {
                size_t off = (size_t)n * DD + ct * 16 + lr;
                float x = (hrawA[off] + num[ct] / (den[ct] + 1e-6f)) * nn;
                hrawA[off] = x;
                sh[ct] += x; sh2[ct] += x * x;
            }
        }
    }

    // stats: reduce se/se2 across lane-groups, then block + atomic
    #pragma unroll
    for (int ct = 0; ct < 4; ++ct) {
        se[ct]  += __shfl_xor(se[ct], 16);  se[ct]  += __shfl_xor(se[ct], 32);
        se2[ct] += __shfl_xor(se2[ct], 16); se2[ct] += __shfl_xor(se2[ct], 32);
    }
    if (ld == 0) {
        #pragma unroll
        for (int ct = 0; ct < 4; ++ct) {
            red[wid][0][ct * 16 + lr] = se[ct];
            red[wid][1][ct * 16 + lr] = se2[ct];
            red[wid][2][ct * 16 + lr] = sh[ct];
            red[wid][3][ct * 16 + lr] = sh2[ct];
        }
    }
    __syncthreads();
    if (threadIdx.x < DD) {
        int t = threadIdx.x;
        float t0 = 0.f, t1 = 0.f, t2 = 0.f, t3 = 0.f;
        #pragma unroll
        for (int w = 0; w < 4; ++w) {
            t0 += red[w][0][t]; t1 += red[w][1][t];
            t2 += red[w][2][t]; t3 += red[w][3][t];
        }
        unsafeAtomicAdd(&stats[t], t0);
        unsafeAtomicAdd(&stats[DD + t], t1);
        unsafeAtomicAdd(&stats[2 * DD + t], t2);
        unsafeAtomicAdd(&stats[3 * DD + t], t3);
    }
}

// ---------------------------------------------------------------------------
// finalize both BNs into fused scale/shift:
// bnAB: [0:64)=A_e [64:128)=B_e [128:192)=A_h [192:256)=B_h
// ---------------------------------------------------------------------------
__global__ void bn_fin2_v10(const float* __restrict__ stats, float Ecnt, float Ncnt,
                            const float* __restrict__ gamma_e, const float* __restrict__ beta_e,
                            const float* __restrict__ gamma_h, const float* __restrict__ beta_h,
                            float* __restrict__ bnAB)
{
    int t = threadIdx.x;   // 128 threads
    if (t < DD) {
        float mu  = stats[t] / Ecnt;
        float var = stats[DD + t] / Ecnt - mu * mu;
        float A = gamma_e[t] * rsqrtf(var + 1e-5f);
        bnAB[t] = A;
        bnAB[DD + t] = beta_e[t] - A * mu;
    } else {
        int cc = t - DD;
        float mu  = stats[2 * DD + cc] / Ncnt;
        float var = stats[3 * DD + cc] / Ncnt - mu * mu;
        float A = gamma_h[cc] * rsqrtf(var + 1e-5f);
        bnAB[2 * DD + cc] = A;
        bnAB[3 * DD + cc] = beta_h[cc] - A * mu;
    }
}

// ---------------------------------------------------------------------------
// final h update: h = h + relu(A*x + B)
// ---------------------------------------------------------------------------
__global__ __launch_bounds__(256) void node_apply_v10(
    const float* __restrict__ hrawX, const float* __restrict__ bnAB,
    float* __restrict__ h, int N)
{
    int cc = (threadIdx.x & 15) * 4;
    float4 A = *(const float4*)(bnAB + 2 * DD + cc);
    float4 B = *(const float4*)(bnAB + 3 * DD + cc);
    int total = N * 16;
    int stride = gridDim.x * blockDim.x;
    for (int u = blockIdx.x * blockDim.x + threadIdx.x; u < total; u += stride) {
        size_t off = ((size_t)(u >> 4)) * DD + ((u & 15) * 4);
        float4 x   = *(const float4*)(hrawX + off);
        float4 hin = *(const float4*)(h + off);
        float4 y;
        y.x = hin.x + fmaxf(A.x * x.x + B.x, 0.f);
        y.y = hin.y + fmaxf(A.y * x.y + B.y, 0.f);
        y.z = hin.z + fmaxf(A.z * x.z + B.z, 0.f);
        y.w = hin.w + fmaxf(A.w * x.w + B.w, 0.f);
        *(float4*)(h + off) = y;
    }
}

// ---------------------------------------------------------------------------
__global__ __launch_bounds__(256) void readout_v10(
    const float* __restrict__ h, const int* __restrict__ gid,
    float* __restrict__ hg, float* __restrict__ counts, int N)
{
    int total = N * 16;
    int stride = gridDim.x * blockDim.x;
    for (int u = blockIdx.x * blockDim.x + threadIdx.x; u < total; u += stride) {
        int n = u >> 4;
        int c = (u & 15) * 4;
        int g = gid[n];
        float4 x = *(const float4*)(h + (size_t)n * DD + c);
        float* p = hg + (size_t)g * DD + c;
        unsafeAtomicAdd(p + 0, x.x);
        unsafeAtomicAdd(p + 1, x.y);
        unsafeAtomicAdd(p + 2, x.z);
        unsafeAtomicAdd(p + 3, x.w);
        if ((u & 15) == 0) unsafeAtomicAdd(&counts[g], 1.0f);
    }
}

__global__ void readout_div_v10(const float* __restrict__ hg,
                                const float* __restrict__ counts,
                                float* __restrict__ out, int GD)
{
    int i = blockIdx.x * blockDim.x + threadIdx.x;
    if (i < GD) {
        int g = i >> 6;
        out[i] = hg[i] / fmaxf(counts[g], 1.0f);
    }
}

// ---------------------------------------------------------------------------
extern "C" void kernel_launch(void* const* d_in, const int* in_sizes, int n_in,
                              void* d_out, int out_size, void* d_ws, size_t ws_size,
                              hipStream_t stream)
{
    const float* nodes_feat = (const float*)d_in[0];
    const float* edges_feat = (const float*)d_in[1];
    const float* nnorm      = (const float*)d_in[2];
    const float* enorm      = (const float*)d_in[3];
    const float* W_h = (const float*)d_in[4];
    const float* b_h = (const float*)d_in[5];
    const float* W_e = (const float*)d_in[6];
    const float* b_e = (const float*)d_in[7];
    const float* Wa  = (const float*)d_in[8];
    const float* ba  = (const float*)d_in[9];
    const float* Wb_ = (const float*)d_in[10];
    const float* bb_ = (const float*)d_in[11];
    const float* Wc  = (const float*)d_in[12];
    const float* bc  = (const float*)d_in[13];
    const float* Wd  = (const float*)d_in[14];
    const float* bd  = (const float*)d_in[15];
    const float* We_ = (const float*)d_in[16];
    const float* be_ = (const float*)d_in[17];
    const float* gamma_h = (const float*)d_in[18];
    const float* beta_h  = (const float*)d_in[19];
    const float* gamma_e = (const float*)d_in[20];
    const float* beta_e  = (const float*)d_in[21];
    const int* esrc = (const int*)d_in[22];
    const int* edst = (const int*)d_in[23];
    const int* gid  = (const int*)d_in[24];

    const int N = in_sizes[0] / DIN;
    const int E = in_sizes[1];
    const int G = out_size / DD;
    const int L = in_sizes[8] / (DD * DD);

    // ---- workspace layout (~254.7 MB) ----
    float* f = (float*)d_ws;
    float* h       = f; f += (size_t)N * DD;
    float* hrawA   = f; f += (size_t)N * DD;     // Ah (in) / x (out), f32
    float* stats   = f; f += 256;
    float* bnAB    = f; f += 256;
    float* hg      = f; f += (size_t)G * DD;   // } zeroed together
    float* gcnt    = f; f += G;                // }
    int*   coffs   = (int*)f; f += (size_t)(N + 2);
    float* enorm_p = f; f += (size_t)E;
    unsigned short* src_p = (unsigned short*)f; f += (size_t)((E + 1) / 2);
    bfu* bp = (bfu*)f;
    bfu* DBh = bp; bp += (size_t)N * 128;
    bfu* Eh  = bp; bp += (size_t)N * DD;
    bfu* e_p = bp; bp += (size_t)E * DD;
    bfu* es  = bp; bp += (size_t)E * DD;
    // setup-only CSR scratch overlays the es region (dead until layer 0)
    int* ccounts = (int*)es;
    int* ccursor = ccounts + (N + 1);
    int* cpart   = ccursor + (N + 1);
    int* csr_eid = cpart + 256;

    dim3 blk(256);

    hipMemsetAsync(hg, 0, ((size_t)G * DD + G) * sizeof(float), stream);
    hipMemsetAsync(ccounts, 0, (size_t)(N + 1) * sizeof(int), stream);

    embed_h_v10<<<(N + 31) / 32, blk, 0, stream>>>(nodes_feat, W_h, b_h, h, N);

    const int M  = N + 1;
    const int CH = (M + 255) / 256;
    csr_hist_v10<<<2048, blk, 0, stream>>>(edst, ccounts, E);
    csr_scan_a_v10<<<256, blk, 0, stream>>>(ccounts, cpart, M, CH);
    csr_scan_b_v10<<<1, blk, 0, stream>>>(cpart);
    csr_scan_c_v10<<<256, blk, 0, stream>>>(ccounts, cpart, coffs, ccursor, M, CH);
    csr_scatter_v10<<<2048, blk, 0, stream>>>(edst, ccursor, csr_eid, E);
    perm_build_v10<<<2048, blk, 0, stream>>>(csr_eid, esrc, enorm, src_p, enorm_p, E);
    embed_e_perm_v10<<<2048, blk, 0, stream>>>(edges_feat, W_e, b_e, csr_eid, e_p, E);

    for (int l = 0; l < L; ++l) {
        node_mm4_v10<<<(N + 63) / 64, blk, 0, stream>>>(
            h, hrawA, bnAB, (l > 0) ? 1 : 0,
            Wa + (size_t)l * DD * DD, ba + (size_t)l * DD,
            Wb_ + (size_t)l * DD * DD, bb_ + (size_t)l * DD,
            Wd + (size_t)l * DD * DD, bd + (size_t)l * DD,
            We_ + (size_t)l * DD * DD, be_ + (size_t)l * DD,
            hrawA, DBh, Eh, N);
        hipMemsetAsync(stats, 0, 256 * sizeof(float), stream);
        edge_fused_v10<<<2048, blk, 0, stream>>>(
            e_p, es, Wc + (size_t)l * DD * DD, bc + (size_t)l * DD,
            bnAB, hrawA, DBh, Eh,
            coffs, src_p, enorm_p, nnorm, stats, N, E,
            (l > 0) ? 1 : 0,
            (l < L - 1) ? 1 : 0);
        bn_fin2_v10<<<1, 128, 0, stream>>>(
            stats, (float)E, (float)N,
            gamma_e + (size_t)l * DD, beta_e + (size_t)l * DD,
            gamma_h + (size_t)l * DD, beta_h + (size_t)l * DD, bnAB);
    }

    node_apply_v10<<<1024, blk, 0, stream>>>(hrawA, bnAB, h, N);
    readout_v10<<<1024, blk, 0, stream>>>(h, gid, hg, gcnt, N);
    readout_div_v10<<<(G * DD + 255) / 256, blk, 0, stream>>>(
        hg, gcnt, (float*)d_out, G * DD);
}